// Round 10
// baseline (227.946 us; speedup 1.0000x reference)
//
#include <hip/hip_runtime.h>

#define NVOX1 524288   // 2*64^3
#define NVOX2 65536    // 2*32^3
#define NVOX4 8192     // 2*16^3

// float offsets into ws (stats area, zeroed each launch)
#define ST_SUM1 16
#define ST_SQ1  24
#define ST_SUM2 32
#define ST_SQ2  48
#define ST_SUM3 64
#define ST_SQ3  96
#define ST_SUM3T 128
#define ST_SQ3T  144
#define ST_SUM2T 160
#define ST_SQ2T  176
#define FLAG_OFF 200   // 2 ints
#define IC_N1 204      // int counters (double as BN counts)
#define IC_N2 205
#define IC_N4 206
#define ST_ZERO 256    // floats memset to 0 each launch

// buffer offsets (in floats)
#define OFF_M1C 512
#define OFF_M2  (OFF_M1C + NVOX1)
#define OFF_M4  (OFF_M2 + NVOX2)
#define OFF_H1  (OFF_M4 + NVOX4)
#define OFF_S2  (OFF_H1 + NVOX1 * 8)
#define OFF_H3  (OFF_S2 + NVOX2 * 16)
#define OFF_T3  (OFF_H3 + NVOX4 * 32)
#define OFF_L1  (OFF_T3 + NVOX2 * 16)
#define OFF_L2  (OFF_L1 + NVOX1)
#define OFF_L4  (OFF_L2 + NVOX2)
#define OFF_BC1 (OFF_L4 + NVOX4)   // 2048 ints
#define OFF_BC2 (OFF_BC1 + 2048)   // 256 ints
#define OFF_BC4 (OFF_BC2 + 256)    // 32 ints

#define EPSBN 1e-5f

// static 2-slot tap table for stride-2 transpose conv (kernel 3, centered)
__device__ __forceinline__ void ttaps(int p, int gin, int* c, int* k, int* ok) {
  c[0] = p >> 1; k[0] = (p & 1) ? 0 : 1; ok[0] = 1;
  int cb = (p + 1) >> 1;
  int o = (p & 1) && (cb < gin);
  c[1] = o ? cb : 0; k[1] = 2; ok[1] = o;
}

// full-wave butterfly over 4-channel partials, then lane0 flush to LDS
__device__ __forceinline__ void stat_flush4(float* sum, float* sq, float* s_sum, float* s_sq, int t) {
#pragma unroll
  for (int off = 1; off < 64; off <<= 1)
#pragma unroll
    for (int c = 0; c < 4; c++) {
      sum[c] += __shfl_xor(sum[c], off, 64);
      sq[c]  += __shfl_xor(sq[c], off, 64);
    }
  if ((t & 63) == 0) {
#pragma unroll
    for (int c = 0; c < 4; c++) { atomicAdd(&s_sum[c], sum[c]); atomicAdd(&s_sq[c], sq[c]); }
  }
}

// ---------- mask format detection ----------
__global__ __launch_bounds__(256) void k_detect(const unsigned int* __restrict__ m,
                                                int* __restrict__ flags) {
  int tid = blockIdx.x * 256 + threadIdx.x;
  int hasf = 0, hasb = 0;
  for (int i = tid; i < NVOX1; i += 256 * 256) {
    unsigned int v = m[i];
    if (v == 0x3F800000u) hasf = 1;
    else if (v > 1u) hasb = 1;
  }
  hasf = __syncthreads_or(hasf);
  hasb = __syncthreads_or(hasb);
  if (threadIdx.x == 0) {
    if (hasf) atomicOr(&flags[0], 1);
    if (hasb) atomicOr(&flags[1], 1);
  }
}

// ---------- canonicalize mask + per-block count ----------
__global__ __launch_bounds__(256) void k_canon(const void* __restrict__ mraw,
                                               int* __restrict__ m1c,
                                               const int* __restrict__ flags,
                                               int* __restrict__ blkcnt1) {
  int idx = blockIdx.x * 256 + threadIdx.x;
  int isf = flags[0], isb = flags[1];
  int v;
  if (isf)      v = (((const float*)mraw)[idx] != 0.f);
  else if (isb) v = (((const unsigned char*)mraw)[idx] != 0);
  else          v = (((const int*)mraw)[idx] != 0);
  m1c[idx] = v;
  int c = __syncthreads_count(v);
  if (threadIdx.x == 0) blkcnt1[blockIdx.x] = c;
}

// ---------- mask downsampling + per-block counts ----------
__global__ __launch_bounds__(256) void k_down1(const int* __restrict__ m1,
                                               int* __restrict__ m2,
                                               int* __restrict__ blkcnt2) {
  int idx = blockIdx.x * 256 + threadIdx.x;
  int x = idx & 31, y = (idx >> 5) & 31, z = (idx >> 10) & 31, b = idx >> 15;
  int any = 0;
#pragma unroll
  for (int dz = 0; dz < 2; dz++)
#pragma unroll
    for (int dy = 0; dy < 2; dy++)
#pragma unroll
      for (int dx = 0; dx < 2; dx++)
        any |= m1[((b * 64 + 2 * z + dz) * 64 + 2 * y + dy) * 64 + 2 * x + dx];
  any = any ? 1 : 0;
  m2[idx] = any;
  int c = __syncthreads_count(any);
  if (threadIdx.x == 0) blkcnt2[blockIdx.x] = c;
}

__global__ __launch_bounds__(256) void k_down2(const int* __restrict__ m2,
                                               int* __restrict__ m4,
                                               int* __restrict__ blkcnt4) {
  int idx = blockIdx.x * 256 + threadIdx.x;
  int x = idx & 15, y = (idx >> 4) & 15, z = (idx >> 8) & 15, b = idx >> 12;
  int any = 0;
#pragma unroll
  for (int dz = 0; dz < 2; dz++)
#pragma unroll
    for (int dy = 0; dy < 2; dy++)
#pragma unroll
      for (int dx = 0; dx < 2; dx++)
        any |= m2[((b * 32 + 2 * z + dz) * 32 + 2 * y + dy) * 32 + 2 * x + dx];
  any = any ? 1 : 0;
  m4[idx] = any;
  int c = __syncthreads_count(any);
  if (threadIdx.x == 0) blkcnt4[blockIdx.x] = c;
}

// ---------- scan ----------
__global__ __launch_bounds__(1024) void k_scan(int* __restrict__ bc1,
                                               int* __restrict__ bc2,
                                               int* __restrict__ bc4,
                                               int* __restrict__ cnts) {
  __shared__ int sA[2048], sB[2048];
  int* a; int n; int outIdx;
  if (blockIdx.x == 0)      { a = bc1; n = 2048; outIdx = IC_N1; }
  else if (blockIdx.x == 1) { a = bc2; n = 256;  outIdx = IC_N2; }
  else                      { a = bc4; n = 32;   outIdx = IC_N4; }
  int t = threadIdx.x;
  int i0 = t, i1 = t + 1024;
  int v0 = (i0 < n) ? a[i0] : 0;
  int v1 = (i1 < n) ? a[i1] : 0;
  sA[i0] = v0; sA[i1] = v1;
  __syncthreads();
  int* src = sA; int* dst = sB;
  for (int st = 1; st < 2048; st <<= 1) {
    int x0 = src[i0]; if (i0 >= st) x0 += src[i0 - st];
    int x1 = src[i1]; if (i1 >= st) x1 += src[i1 - st];
    dst[i0] = x0; dst[i1] = x1;
    __syncthreads();
    int* tmp = src; src = dst; dst = tmp;
  }
  if (i0 < n) a[i0] = src[i0] - v0;
  if (i1 < n) a[i1] = src[i1] - v1;
  if (t == 0) cnts[outIdx] = src[2047];
}

// ---------- scatter ----------
__global__ __launch_bounds__(256) void k_scatter(const int* __restrict__ m1,
                                                 const int* __restrict__ m2,
                                                 const int* __restrict__ m4,
                                                 const int* __restrict__ bc1,
                                                 const int* __restrict__ bc2,
                                                 const int* __restrict__ bc4,
                                                 int* __restrict__ list1,
                                                 int* __restrict__ list2,
                                                 int* __restrict__ list4) {
  __shared__ int s_w[4];
  int bid = blockIdx.x, t = threadIdx.x;
  const int* mask; const int* base; int* list; int lb;
  if (bid < 2048)      { mask = m1; base = bc1; list = list1; lb = bid; }
  else if (bid < 2304) { mask = m2; base = bc2; list = list2; lb = bid - 2048; }
  else                 { mask = m4; base = bc4; list = list4; lb = bid - 2304; }
  int idx = lb * 256 + t;
  int act = mask[idx];
  unsigned long long b = __ballot(act != 0);
  int lane = t & 63, wid = t >> 6;
  if (lane == 0) s_w[wid] = __popcll(b);
  __syncthreads();
  int wbase = 0;
  for (int i = 0; i < wid; i++) wbase += s_w[i];
  if (act) {
    int pre = __popcll(b & ((1ull << lane) - 1ull));
    list[base[lb] + wbase + pre] = idx;
  }
}

// ---------- conv1: thread = (voxel), quad g of 2 (4 co each) ----------
__global__ __launch_bounds__(256) void k_conv1(const float* __restrict__ x,
                                               const int* __restrict__ m1,
                                               const int* __restrict__ list1,
                                               const int* __restrict__ cnts,
                                               const float* __restrict__ w,
                                               float* __restrict__ h1,
                                               float* __restrict__ stats) {
  __shared__ float s_w[27 * 4 * 4];   // [tap][ci4][co4]
  __shared__ float s_sum[4], s_sq[4];
  int t = threadIdx.x, g = blockIdx.y;
  for (int i = t; i < 108; i += 256)
    *(float4*)(s_w + i * 4) = *(const float4*)(w + i * 8 + g * 4);
  if (t < 4) { s_sum[t] = 0.f; s_sq[t] = 0.f; }
  __syncthreads();
  int n = cnts[IC_N1];
  float sum[4], sq[4];
#pragma unroll
  for (int c = 0; c < 4; c++) { sum[c] = 0.f; sq[c] = 0.f; }
  for (int i = blockIdx.x * 256 + t; i < n; i += gridDim.x * 256) {
    int v = list1[i];
    int vx = v & 63, vy = (v >> 6) & 63, vz = (v >> 12) & 63, vb = v >> 18;
    float acc[4];
#pragma unroll
    for (int c = 0; c < 4; c++) acc[c] = 0.f;
#pragma unroll
    for (int kd = 0; kd < 3; kd++) { int d = vz + kd - 1; if ((unsigned)d >= 64u) continue;
#pragma unroll
      for (int kh = 0; kh < 3; kh++) { int h = vy + kh - 1; if ((unsigned)h >= 64u) continue;
#pragma unroll
        for (int kw = 0; kw < 3; kw++) { int ww = vx + kw - 1; if ((unsigned)ww >= 64u) continue;
          int ni = ((vb * 64 + d) * 64 + h) * 64 + ww;
          if (!m1[ni]) continue;
          float4 ip = *(const float4*)(x + (size_t)ni * 4);
          const float* wp = s_w + ((kd * 3 + kh) * 3 + kw) * 16;
          float rr[4] = {ip.x, ip.y, ip.z, ip.w};
#pragma unroll
          for (int ci = 0; ci < 4; ci++)
#pragma unroll
            for (int c = 0; c < 4; c++) acc[c] = fmaf(rr[ci], wp[ci * 4 + c], acc[c]);
        } } }
    *(float4*)(h1 + (size_t)v * 8 + g * 4) = make_float4(acc[0], acc[1], acc[2], acc[3]);
#pragma unroll
    for (int c = 0; c < 4; c++) { sum[c] += acc[c]; sq[c] += acc[c] * acc[c]; }
  }
  stat_flush4(sum, sq, s_sum, s_sq, t);
  __syncthreads();
  if (t < 4) {
    if (s_sum[t] != 0.f) atomicAdd(&stats[ST_SUM1 + g * 4 + t], s_sum[t]);
    if (s_sq[t]  != 0.f) atomicAdd(&stats[ST_SQ1 + g * 4 + t], s_sq[t]);
  }
}

// ---------- conv2: quad g of 4; BN1+relu inline ----------
__global__ __launch_bounds__(256) void k_conv2(const float* __restrict__ h1,
                                               const int* __restrict__ m1,
                                               const int* __restrict__ list2,
                                               const int* __restrict__ cnts,
                                               const float* __restrict__ w,
                                               const float* __restrict__ g1,
                                               const float* __restrict__ b1,
                                               float* __restrict__ s2,
                                               float* __restrict__ stats) {
  __shared__ float s_w[27 * 8 * 4];   // [tap][ci8][co4]
  __shared__ float s_sc[8], s_bi[8];
  __shared__ float s_sum[4], s_sq[4];
  int t = threadIdx.x, g = blockIdx.y;
  for (int i = t; i < 216; i += 256)
    *(float4*)(s_w + i * 4) = *(const float4*)(w + i * 16 + g * 4);
  if (t < 8) {
    float cnt = fmaxf((float)cnts[IC_N1], 1.f);
    float mean = stats[ST_SUM1 + t] / cnt;
    float var = fmaxf(stats[ST_SQ1 + t] / cnt - mean * mean, 0.f);
    float sc = g1[t] * rsqrtf(var + EPSBN);
    s_sc[t] = sc; s_bi[t] = b1[t] - mean * sc;
  }
  if (t < 4) { s_sum[t] = 0.f; s_sq[t] = 0.f; }
  __syncthreads();
  int n = cnts[IC_N2];
  float sum[4], sq[4];
#pragma unroll
  for (int c = 0; c < 4; c++) { sum[c] = 0.f; sq[c] = 0.f; }
  for (int i = blockIdx.x * 256 + t; i < n; i += gridDim.x * 256) {
    int v = list2[i];
    int vx = v & 31, vy = (v >> 5) & 31, vz = (v >> 10) & 31, vb = v >> 15;
    float acc[4];
#pragma unroll
    for (int c = 0; c < 4; c++) acc[c] = 0.f;
#pragma unroll
    for (int kd = 0; kd < 3; kd++) { int d = 2 * vz + kd - 1; if (d < 0) continue;
#pragma unroll
      for (int kh = 0; kh < 3; kh++) { int h = 2 * vy + kh - 1; if (h < 0) continue;
#pragma unroll
        for (int kw = 0; kw < 3; kw++) { int ww = 2 * vx + kw - 1; if (ww < 0) continue;
          int ni = ((vb * 64 + d) * 64 + h) * 64 + ww;
          if (!m1[ni]) continue;
          float4 i0 = *(const float4*)(h1 + (size_t)ni * 8);
          float4 i1 = *(const float4*)(h1 + (size_t)ni * 8 + 4);
          float r[8] = {i0.x, i0.y, i0.z, i0.w, i1.x, i1.y, i1.z, i1.w};
          const float* wp = s_w + ((kd * 3 + kh) * 3 + kw) * 32;
#pragma unroll
          for (int ci = 0; ci < 8; ci++) {
            float vv = fmaxf(fmaf(r[ci], s_sc[ci], s_bi[ci]), 0.f);
#pragma unroll
            for (int c = 0; c < 4; c++) acc[c] = fmaf(vv, wp[ci * 4 + c], acc[c]);
          }
        } } }
    *(float4*)(s2 + (size_t)v * 16 + g * 4) = make_float4(acc[0], acc[1], acc[2], acc[3]);
#pragma unroll
    for (int c = 0; c < 4; c++) { sum[c] += acc[c]; sq[c] += acc[c] * acc[c]; }
  }
  stat_flush4(sum, sq, s_sum, s_sq, t);
  __syncthreads();
  if (t < 4) {
    if (s_sum[t] != 0.f) atomicAdd(&stats[ST_SUM2 + g * 4 + t], s_sum[t]);
    if (s_sq[t]  != 0.f) atomicAdd(&stats[ST_SQ2 + g * 4 + t], s_sq[t]);
  }
}

// ---------- conv3: quad g of 8; BN2+relu inline ----------
__global__ __launch_bounds__(256) void k_conv3(const float* __restrict__ s2raw,
                                               const int* __restrict__ m2,
                                               const int* __restrict__ list4,
                                               const int* __restrict__ cnts,
                                               const float* __restrict__ w,
                                               const float* __restrict__ g2,
                                               const float* __restrict__ b2,
                                               float* __restrict__ h3,
                                               float* __restrict__ stats) {
  __shared__ float s_w[27 * 16 * 4];  // [tap][ci16][co4]
  __shared__ float s_sc[16], s_bi[16];
  __shared__ float s_sum[4], s_sq[4];
  int t = threadIdx.x, g = blockIdx.y;
  for (int i = t; i < 432; i += 256)
    *(float4*)(s_w + i * 4) = *(const float4*)(w + i * 32 + g * 4);
  if (t < 16) {
    float cnt = fmaxf((float)cnts[IC_N2], 1.f);
    float mean = stats[ST_SUM2 + t] / cnt;
    float var = fmaxf(stats[ST_SQ2 + t] / cnt - mean * mean, 0.f);
    float sc = g2[t] * rsqrtf(var + EPSBN);
    s_sc[t] = sc; s_bi[t] = b2[t] - mean * sc;
  }
  if (t < 4) { s_sum[t] = 0.f; s_sq[t] = 0.f; }
  __syncthreads();
  int n = cnts[IC_N4];
  float sum[4], sq[4];
#pragma unroll
  for (int c = 0; c < 4; c++) { sum[c] = 0.f; sq[c] = 0.f; }
  for (int i = blockIdx.x * 256 + t; i < n; i += gridDim.x * 256) {
    int v = list4[i];
    int vx = v & 15, vy = (v >> 4) & 15, vz = (v >> 8) & 15, vb = v >> 12;
    float acc[4];
#pragma unroll
    for (int c = 0; c < 4; c++) acc[c] = 0.f;
#pragma unroll
    for (int kd = 0; kd < 3; kd++) { int d = 2 * vz + kd - 1; if (d < 0) continue;
#pragma unroll
      for (int kh = 0; kh < 3; kh++) { int h = 2 * vy + kh - 1; if (h < 0) continue;
#pragma unroll
        for (int kw = 0; kw < 3; kw++) { int ww = 2 * vx + kw - 1; if (ww < 0) continue;
          int ni = ((vb * 32 + d) * 32 + h) * 32 + ww;
          if (!m2[ni]) continue;
          const float4* ip = (const float4*)(s2raw + (size_t)ni * 16);
          const float* wp = s_w + ((kd * 3 + kh) * 3 + kw) * 64;
#pragma unroll
          for (int cq = 0; cq < 4; cq++) {
            float4 q = ip[cq];
            float rr[4] = {q.x, q.y, q.z, q.w};
#pragma unroll
            for (int j = 0; j < 4; j++) {
              int ci = cq * 4 + j;
              float vv = fmaxf(fmaf(rr[j], s_sc[ci], s_bi[ci]), 0.f);
#pragma unroll
              for (int c = 0; c < 4; c++) acc[c] = fmaf(vv, wp[ci * 4 + c], acc[c]);
            }
          }
        } } }
    *(float4*)(h3 + (size_t)v * 32 + g * 4) = make_float4(acc[0], acc[1], acc[2], acc[3]);
#pragma unroll
    for (int c = 0; c < 4; c++) { sum[c] += acc[c]; sq[c] += acc[c] * acc[c]; }
  }
  stat_flush4(sum, sq, s_sum, s_sq, t);
  __syncthreads();
  if (t < 4) {
    if (s_sum[t] != 0.f) atomicAdd(&stats[ST_SUM3 + g * 4 + t], s_sum[t]);
    if (s_sq[t]  != 0.f) atomicAdd(&stats[ST_SQ3 + g * 4 + t], s_sq[t]);
  }
}

// ---------- convt3: quad g of 4; BN3+relu inline ----------
__global__ __launch_bounds__(256) void k_convt3(const float* __restrict__ h3raw,
                                                const int* __restrict__ m4,
                                                const int* __restrict__ list2,
                                                const int* __restrict__ cnts,
                                                const float* __restrict__ w,
                                                const float* __restrict__ g3,
                                                const float* __restrict__ b3,
                                                float* __restrict__ t3,
                                                float* __restrict__ stats) {
  __shared__ float s_w[27 * 32 * 4];  // [tap][ci32][co4]
  __shared__ float s_sc[32], s_bi[32];
  __shared__ float s_sum[4], s_sq[4];
  int t = threadIdx.x, g = blockIdx.y;
  for (int i = t; i < 864; i += 256)
    *(float4*)(s_w + i * 4) = *(const float4*)(w + i * 16 + g * 4);
  if (t < 32) {
    float cnt = fmaxf((float)cnts[IC_N4], 1.f);
    float mean = stats[ST_SUM3 + t] / cnt;
    float var = fmaxf(stats[ST_SQ3 + t] / cnt - mean * mean, 0.f);
    float sc = g3[t] * rsqrtf(var + EPSBN);
    s_sc[t] = sc; s_bi[t] = b3[t] - mean * sc;
  }
  if (t < 4) { s_sum[t] = 0.f; s_sq[t] = 0.f; }
  __syncthreads();
  int n = cnts[IC_N2];
  float sum[4], sq[4];
#pragma unroll
  for (int c = 0; c < 4; c++) { sum[c] = 0.f; sq[c] = 0.f; }
  for (int i = blockIdx.x * 256 + t; i < n; i += gridDim.x * 256) {
    int v = list2[i];
    int px = v & 31, py = (v >> 5) & 31, pz = (v >> 10) & 31, vb = v >> 15;
    int czv[2], kzv[2], okz[2], cyv[2], kyv[2], oky[2], cxv[2], kxv[2], okx[2];
    ttaps(pz, 16, czv, kzv, okz);
    ttaps(py, 16, cyv, kyv, oky);
    ttaps(px, 16, cxv, kxv, okx);
    float acc[4];
#pragma unroll
    for (int c = 0; c < 4; c++) acc[c] = 0.f;
#pragma unroll
    for (int dz = 0; dz < 2; dz++)
#pragma unroll
      for (int dy = 0; dy < 2; dy++)
#pragma unroll
        for (int dx = 0; dx < 2; dx++) {
          if (!(okz[dz] & oky[dy] & okx[dx])) continue;
          int ni = ((vb * 16 + czv[dz]) * 16 + cyv[dy]) * 16 + cxv[dx];
          if (!m4[ni]) continue;
          const float4* ip = (const float4*)(h3raw + (size_t)ni * 32);
          const float* wp = s_w + ((kzv[dz] * 3 + kyv[dy]) * 3 + kxv[dx]) * 128;
#pragma unroll
          for (int cq = 0; cq < 8; cq++) {
            float4 q = ip[cq];
            float rr[4] = {q.x, q.y, q.z, q.w};
#pragma unroll
            for (int j = 0; j < 4; j++) {
              int ci = cq * 4 + j;
              float vv = fmaxf(fmaf(rr[j], s_sc[ci], s_bi[ci]), 0.f);
#pragma unroll
              for (int c = 0; c < 4; c++) acc[c] = fmaf(vv, wp[ci * 4 + c], acc[c]);
            }
          }
        }
    *(float4*)(t3 + (size_t)v * 16 + g * 4) = make_float4(acc[0], acc[1], acc[2], acc[3]);
#pragma unroll
    for (int c = 0; c < 4; c++) { sum[c] += acc[c]; sq[c] += acc[c] * acc[c]; }
  }
  stat_flush4(sum, sq, s_sum, s_sq, t);
  __syncthreads();
  if (t < 4) {
    if (s_sum[t] != 0.f) atomicAdd(&stats[ST_SUM3T + g * 4 + t], s_sum[t]);
    if (s_sq[t]  != 0.f) atomicAdd(&stats[ST_SQ3T + g * 4 + t], s_sq[t]);
  }
}

// ---------- convt2: quad g of 4; concat; raw -> d_out ----------
__global__ __launch_bounds__(256) void k_convt2(const float* __restrict__ t3raw,
                                                const float* __restrict__ s2raw,
                                                const int* __restrict__ m2,
                                                const int* __restrict__ list1,
                                                const int* __restrict__ cnts,
                                                const float* __restrict__ w,
                                                const float* __restrict__ g3t,
                                                const float* __restrict__ b3t,
                                                const float* __restrict__ g2,
                                                const float* __restrict__ b2,
                                                float* __restrict__ outraw,
                                                float* __restrict__ stats) {
  __shared__ float s_w[27 * 32 * 4];  // [tap][ci32][co4]
  __shared__ float s_sct[16], s_bit[16], s_sc2[16], s_bi2[16];
  __shared__ float s_sum[4], s_sq[4];
  int t = threadIdx.x, g = blockIdx.y;
  for (int i = t; i < 864; i += 256)
    *(float4*)(s_w + i * 4) = *(const float4*)(w + i * 16 + g * 4);
  if (t < 16) {
    float cnt = fmaxf((float)cnts[IC_N2], 1.f);
    float mean = stats[ST_SUM3T + t] / cnt;
    float var = fmaxf(stats[ST_SQ3T + t] / cnt - mean * mean, 0.f);
    float sc = g3t[t] * rsqrtf(var + EPSBN);
    s_sct[t] = sc; s_bit[t] = b3t[t] - mean * sc;
    float mean2 = stats[ST_SUM2 + t] / cnt;
    float var2 = fmaxf(stats[ST_SQ2 + t] / cnt - mean2 * mean2, 0.f);
    float sc2 = g2[t] * rsqrtf(var2 + EPSBN);
    s_sc2[t] = sc2; s_bi2[t] = b2[t] - mean2 * sc2;
  }
  if (t < 4) { s_sum[t] = 0.f; s_sq[t] = 0.f; }
  __syncthreads();
  int n = cnts[IC_N1];
  float sum[4], sq[4];
#pragma unroll
  for (int c = 0; c < 4; c++) { sum[c] = 0.f; sq[c] = 0.f; }
  for (int i = blockIdx.x * 256 + t; i < n; i += gridDim.x * 256) {
    int v = list1[i];
    int px = v & 63, py = (v >> 6) & 63, pz = (v >> 12) & 63, vb = v >> 18;
    int czv[2], kzv[2], okz[2], cyv[2], kyv[2], oky[2], cxv[2], kxv[2], okx[2];
    ttaps(pz, 32, czv, kzv, okz);
    ttaps(py, 32, cyv, kyv, oky);
    ttaps(px, 32, cxv, kxv, okx);
    float acc[4];
#pragma unroll
    for (int c = 0; c < 4; c++) acc[c] = 0.f;
#pragma unroll
    for (int dz = 0; dz < 2; dz++)
#pragma unroll
      for (int dy = 0; dy < 2; dy++)
#pragma unroll
        for (int dx = 0; dx < 2; dx++) {
          if (!(okz[dz] & oky[dy] & okx[dx])) continue;
          int ni = ((vb * 32 + czv[dz]) * 32 + cyv[dy]) * 32 + cxv[dx];
          if (!m2[ni]) continue;
          const float4* tp = (const float4*)(t3raw + (size_t)ni * 16);
          const float4* sp = (const float4*)(s2raw + (size_t)ni * 16);
          const float* wp = s_w + ((kzv[dz] * 3 + kyv[dy]) * 3 + kxv[dx]) * 128;
#pragma unroll
          for (int cq = 0; cq < 4; cq++) {
            float4 q = tp[cq];
            float rr[4] = {q.x, q.y, q.z, q.w};
#pragma unroll
            for (int j = 0; j < 4; j++) {
              int ci = cq * 4 + j;
              float vv = fmaxf(fmaf(rr[j], s_sct[ci], s_bit[ci]), 0.f);
#pragma unroll
              for (int c = 0; c < 4; c++) acc[c] = fmaf(vv, wp[ci * 4 + c], acc[c]);
            }
          }
#pragma unroll
          for (int cq = 0; cq < 4; cq++) {
            float4 q = sp[cq];
            float rr[4] = {q.x, q.y, q.z, q.w};
#pragma unroll
            for (int j = 0; j < 4; j++) {
              int ci = cq * 4 + j;
              float vv = fmaf(rr[j], s_sc2[ci], s_bi2[ci]);
#pragma unroll
              for (int c = 0; c < 4; c++) acc[c] = fmaf(vv, wp[(16 + ci) * 4 + c], acc[c]);
            }
          }
        }
    *(float4*)(outraw + (size_t)v * 16 + g * 4) = make_float4(acc[0], acc[1], acc[2], acc[3]);
#pragma unroll
    for (int c = 0; c < 4; c++) { sum[c] += acc[c]; sq[c] += acc[c] * acc[c]; }
  }
  stat_flush4(sum, sq, s_sum, s_sq, t);
  __syncthreads();
  if (t < 4) {
    if (s_sum[t] != 0.f) atomicAdd(&stats[ST_SUM2T + g * 4 + t], s_sum[t]);
    if (s_sq[t]  != 0.f) atomicAdd(&stats[ST_SQ2T + g * 4 + t], s_sq[t]);
  }
}

// ---------- final (DENSE): BN2t+relu(out) concat BN1(h1) -> 1x1; zeros for inactive ----------
__global__ __launch_bounds__(256) void k_final(float* __restrict__ out,
                                               const float* __restrict__ h1raw,
                                               const int* __restrict__ m1,
                                               const int* __restrict__ cnts,
                                               const float* __restrict__ g2t,
                                               const float* __restrict__ b2t,
                                               const float* __restrict__ g1,
                                               const float* __restrict__ b1,
                                               const float* __restrict__ w1x1,
                                               const float* __restrict__ stats) {
  __shared__ float s_sc[16], s_bi[16], s_sc1[8], s_bi1[8], s_w[384];
  int t = threadIdx.x;
  for (int i = t; i < 384; i += 256) s_w[i] = w1x1[i];
  if (t < 16) {
    float cnt = fmaxf((float)cnts[IC_N1], 1.f);
    float mean = stats[ST_SUM2T + t] / cnt;
    float var = fmaxf(stats[ST_SQ2T + t] / cnt - mean * mean, 0.f);
    float sc = g2t[t] * rsqrtf(var + EPSBN);
    s_sc[t] = sc; s_bi[t] = b2t[t] - mean * sc;
  }
  if (t < 8) {
    float cnt = fmaxf((float)cnts[IC_N1], 1.f);
    float mean = stats[ST_SUM1 + t] / cnt;
    float var = fmaxf(stats[ST_SQ1 + t] / cnt - mean * mean, 0.f);
    float sc = g1[t] * rsqrtf(var + EPSBN);
    s_sc1[t] = sc; s_bi1[t] = b1[t] - mean * sc;
  }
  __syncthreads();
  int v = blockIdx.x * 256 + t;
  float* op = out + (size_t)v * 16;
  float4* op4 = (float4*)op;
  if (!m1[v]) {
    float4 z = {0.f, 0.f, 0.f, 0.f};
    op4[0] = z; op4[1] = z; op4[2] = z; op4[3] = z;
    return;
  }
  float t2[16];
  {
#pragma unroll
    for (int cq = 0; cq < 4; cq++) {
      float4 q = op4[cq];
      t2[cq * 4 + 0] = fmaxf(fmaf(q.x, s_sc[cq * 4 + 0], s_bi[cq * 4 + 0]), 0.f);
      t2[cq * 4 + 1] = fmaxf(fmaf(q.y, s_sc[cq * 4 + 1], s_bi[cq * 4 + 1]), 0.f);
      t2[cq * 4 + 2] = fmaxf(fmaf(q.z, s_sc[cq * 4 + 2], s_bi[cq * 4 + 2]), 0.f);
      t2[cq * 4 + 3] = fmaxf(fmaf(q.w, s_sc[cq * 4 + 3], s_bi[cq * 4 + 3]), 0.f);
    }
  }
  float s1v[8];
  {
    const float4* sp4 = (const float4*)(h1raw + (size_t)v * 8);
#pragma unroll
    for (int cq = 0; cq < 2; cq++) {
      float4 q = sp4[cq];
      s1v[cq * 4 + 0] = fmaf(q.x, s_sc1[cq * 4 + 0], s_bi1[cq * 4 + 0]);
      s1v[cq * 4 + 1] = fmaf(q.y, s_sc1[cq * 4 + 1], s_bi1[cq * 4 + 1]);
      s1v[cq * 4 + 2] = fmaf(q.z, s_sc1[cq * 4 + 2], s_bi1[cq * 4 + 2]);
      s1v[cq * 4 + 3] = fmaf(q.w, s_sc1[cq * 4 + 3], s_bi1[cq * 4 + 3]);
    }
  }
  float o[16];
#pragma unroll
  for (int oc = 0; oc < 16; oc++) o[oc] = 0.f;
#pragma unroll
  for (int c = 0; c < 16; c++) {
    float vv = t2[c];
#pragma unroll
    for (int oc = 0; oc < 16; oc++) o[oc] = fmaf(vv, s_w[c * 16 + oc], o[oc]);
  }
#pragma unroll
  for (int c = 0; c < 8; c++) {
    float vv = s1v[c];
#pragma unroll
    for (int oc = 0; oc < 16; oc++) o[oc] = fmaf(vv, s_w[(16 + c) * 16 + oc], o[oc]);
  }
#pragma unroll
  for (int cq = 0; cq < 4; cq++) {
    float4 q = {o[cq * 4 + 0], o[cq * 4 + 1], o[cq * 4 + 2], o[cq * 4 + 3]};
    op4[cq] = q;
  }
}

extern "C" void kernel_launch(void* const* d_in, const int* in_sizes, int n_in,
                              void* d_out, int out_size, void* d_ws, size_t ws_size,
                              hipStream_t stream) {
  const float* x    = (const float*)d_in[0];
  const void*  mraw = d_in[1];
  const float* w1   = (const float*)d_in[2];
  const float* g1   = (const float*)d_in[3];
  const float* b1   = (const float*)d_in[4];
  const float* w2   = (const float*)d_in[5];
  const float* g2   = (const float*)d_in[6];
  const float* b2   = (const float*)d_in[7];
  const float* w3   = (const float*)d_in[8];
  const float* g3   = (const float*)d_in[9];
  const float* b3   = (const float*)d_in[10];
  const float* w3t  = (const float*)d_in[11];
  const float* g3t  = (const float*)d_in[12];
  const float* b3t  = (const float*)d_in[13];
  const float* w2t  = (const float*)d_in[14];
  const float* g2t  = (const float*)d_in[15];
  const float* b2t  = (const float*)d_in[16];
  const float* w1x1 = (const float*)d_in[17];

  float* ws = (float*)d_ws;
  float* stats = ws;
  int* cnts = (int*)ws;
  int* flags = (int*)(ws + FLAG_OFF);
  int* m1c = (int*)(ws + OFF_M1C);
  int* m2  = (int*)(ws + OFF_M2);
  int* m4  = (int*)(ws + OFF_M4);
  float* h1 = ws + OFF_H1;
  float* s2 = ws + OFF_S2;
  float* h3 = ws + OFF_H3;
  float* t3 = ws + OFF_T3;
  int* list1 = (int*)(ws + OFF_L1);
  int* list2 = (int*)(ws + OFF_L2);
  int* list4 = (int*)(ws + OFF_L4);
  int* bc1 = (int*)(ws + OFF_BC1);
  int* bc2 = (int*)(ws + OFF_BC2);
  int* bc4 = (int*)(ws + OFF_BC4);
  float* out = (float*)d_out;

  hipMemsetAsync(ws, 0, ST_ZERO * sizeof(float), stream);
  k_detect<<<256, 256, 0, stream>>>((const unsigned int*)mraw, flags);
  k_canon<<<NVOX1 / 256, 256, 0, stream>>>(mraw, m1c, flags, bc1);
  k_down1<<<NVOX2 / 256, 256, 0, stream>>>(m1c, m2, bc2);
  k_down2<<<NVOX4 / 256, 256, 0, stream>>>(m2, m4, bc4);
  k_scan<<<3, 1024, 0, stream>>>(bc1, bc2, bc4, cnts);
  k_scatter<<<2048 + 256 + 32, 256, 0, stream>>>(m1c, m2, m4, bc1, bc2, bc4, list1, list2, list4);
  k_conv1<<<dim3(256, 2), 256, 0, stream>>>(x, m1c, list1, cnts, w1, h1, stats);
  k_conv2<<<dim3(256, 4), 256, 0, stream>>>(h1, m1c, list2, cnts, w2, g1, b1, s2, stats);
  k_conv3<<<dim3(32, 8), 256, 0, stream>>>(s2, m2, list4, cnts, w3, g2, b2, h3, stats);
  k_convt3<<<dim3(256, 4), 256, 0, stream>>>(h3, m4, list2, cnts, w3t, g3, b3, t3, stats);
  k_convt2<<<dim3(256, 4), 256, 0, stream>>>(t3, s2, m2, list1, cnts, w2t, g3t, b3t, g2, b2, out, stats);
  k_final<<<NVOX1 / 256, 256, 0, stream>>>(out, h1, m1c, cnts, g2t, b2t, g1, b1, w1x1, stats);
}

// Round 11
// 191.362 us; speedup vs baseline: 1.1912x; 1.1912x over previous
//
#include <hip/hip_runtime.h>

#define NVOX1 524288   // 2*64^3
#define NVOX2 65536    // 2*32^3
#define NVOX4 8192     // 2*16^3

// float offsets into ws (stats area, zeroed each launch)
#define ST_SUM1 16
#define ST_SQ1  24
#define ST_SUM2 32
#define ST_SQ2  48
#define ST_SUM3 64
#define ST_SQ3  96
#define ST_SUM3T 128
#define ST_SQ3T  144
#define ST_SUM2T 160
#define ST_SQ2T  176
#define FLAG_OFF 200   // 2 ints
#define IC_N1 204      // int counters (double as BN counts)
#define IC_N2 205
#define IC_N4 206
#define ST_ZERO 256    // floats memset to 0 each launch

// buffer offsets (in floats)
#define OFF_M1C 512
#define OFF_M2  (OFF_M1C + NVOX1)
#define OFF_M4  (OFF_M2 + NVOX2)
#define OFF_H1  (OFF_M4 + NVOX4)
#define OFF_S2  (OFF_H1 + NVOX1 * 8)
#define OFF_H3  (OFF_S2 + NVOX2 * 16)
#define OFF_T3  (OFF_H3 + NVOX4 * 32)
#define OFF_L1  (OFF_T3 + NVOX2 * 16)
#define OFF_L2  (OFF_L1 + NVOX1)
#define OFF_L4  (OFF_L2 + NVOX2)
#define OFF_BC1 (OFF_L4 + NVOX4)   // 2048 ints
#define OFF_BC2 (OFF_BC1 + 2048)   // 256 ints
#define OFF_BC4 (OFF_BC2 + 256)    // 32 ints
#define OFF_NB1  (OFF_BC4 + 32)      // NVOX1 ints (conv1 27b)
#define OFF_NB2  (OFF_NB1 + NVOX1)   // NVOX2 ints (conv2 27b)
#define OFF_NB4  (OFF_NB2 + NVOX2)   // NVOX4 ints (conv3 27b)
#define OFF_NBT3 (OFF_NB4 + NVOX4)   // NVOX2 ints (convt3 8b)
#define OFF_NBT2 (OFF_NBT3 + NVOX2)  // NVOX1 ints (convt2 8b)

#define EPSBN 1e-5f

// static 2-slot tap table for stride-2 transpose conv (kernel 3, centered)
__device__ __forceinline__ void ttaps(int p, int gin, int* c, int* k, int* ok) {
  c[0] = p >> 1; k[0] = (p & 1) ? 0 : 1; ok[0] = 1;
  int cb = (p + 1) >> 1;
  int o = (p & 1) && (cb < gin);
  c[1] = o ? cb : 0; k[1] = 2; ok[1] = o;
}

// full-wave butterfly over 8-channel partials, then lane0 flush
__device__ __forceinline__ void stat_flush8(float* sum, float* sq, float* s_sum, float* s_sq, int t) {
#pragma unroll
  for (int off = 1; off < 64; off <<= 1)
#pragma unroll
    for (int c = 0; c < 8; c++) {
      sum[c] += __shfl_xor(sum[c], off, 64);
      sq[c]  += __shfl_xor(sq[c], off, 64);
    }
  if ((t & 63) == 0) {
#pragma unroll
    for (int c = 0; c < 8; c++) { atomicAdd(&s_sum[c], sum[c]); atomicAdd(&s_sq[c], sq[c]); }
  }
}

// ---------- mask format detection ----------
__global__ __launch_bounds__(256) void k_detect(const unsigned int* __restrict__ m,
                                                int* __restrict__ flags) {
  int tid = blockIdx.x * 256 + threadIdx.x;
  int hasf = 0, hasb = 0;
  for (int i = tid; i < NVOX1; i += 256 * 256) {
    unsigned int v = m[i];
    if (v == 0x3F800000u) hasf = 1;
    else if (v > 1u) hasb = 1;
  }
  hasf = __syncthreads_or(hasf);
  hasb = __syncthreads_or(hasb);
  if (threadIdx.x == 0) {
    if (hasf) atomicOr(&flags[0], 1);
    if (hasb) atomicOr(&flags[1], 1);
  }
}

// ---------- canonicalize mask + per-block count ----------
__global__ __launch_bounds__(256) void k_canon(const void* __restrict__ mraw,
                                               int* __restrict__ m1c,
                                               const int* __restrict__ flags,
                                               int* __restrict__ blkcnt1) {
  int idx = blockIdx.x * 256 + threadIdx.x;
  int isf = flags[0], isb = flags[1];
  int v;
  if (isf)      v = (((const float*)mraw)[idx] != 0.f);
  else if (isb) v = (((const unsigned char*)mraw)[idx] != 0);
  else          v = (((const int*)mraw)[idx] != 0);
  m1c[idx] = v;
  int c = __syncthreads_count(v);
  if (threadIdx.x == 0) blkcnt1[blockIdx.x] = c;
}

// ---------- mask downsampling + per-block counts ----------
__global__ __launch_bounds__(256) void k_down1(const int* __restrict__ m1,
                                               int* __restrict__ m2,
                                               int* __restrict__ blkcnt2) {
  int idx = blockIdx.x * 256 + threadIdx.x;
  int x = idx & 31, y = (idx >> 5) & 31, z = (idx >> 10) & 31, b = idx >> 15;
  int any = 0;
#pragma unroll
  for (int dz = 0; dz < 2; dz++)
#pragma unroll
    for (int dy = 0; dy < 2; dy++)
#pragma unroll
      for (int dx = 0; dx < 2; dx++)
        any |= m1[((b * 64 + 2 * z + dz) * 64 + 2 * y + dy) * 64 + 2 * x + dx];
  any = any ? 1 : 0;
  m2[idx] = any;
  int c = __syncthreads_count(any);
  if (threadIdx.x == 0) blkcnt2[blockIdx.x] = c;
}

__global__ __launch_bounds__(256) void k_down2(const int* __restrict__ m2,
                                               int* __restrict__ m4,
                                               int* __restrict__ blkcnt4) {
  int idx = blockIdx.x * 256 + threadIdx.x;
  int x = idx & 15, y = (idx >> 4) & 15, z = (idx >> 8) & 15, b = idx >> 12;
  int any = 0;
#pragma unroll
  for (int dz = 0; dz < 2; dz++)
#pragma unroll
    for (int dy = 0; dy < 2; dy++)
#pragma unroll
      for (int dx = 0; dx < 2; dx++)
        any |= m2[((b * 32 + 2 * z + dz) * 32 + 2 * y + dy) * 32 + 2 * x + dx];
  any = any ? 1 : 0;
  m4[idx] = any;
  int c = __syncthreads_count(any);
  if (threadIdx.x == 0) blkcnt4[blockIdx.x] = c;
}

// ---------- scan ----------
__global__ __launch_bounds__(1024) void k_scan(int* __restrict__ bc1,
                                               int* __restrict__ bc2,
                                               int* __restrict__ bc4,
                                               int* __restrict__ cnts) {
  __shared__ int sA[2048], sB[2048];
  int* a; int n; int outIdx;
  if (blockIdx.x == 0)      { a = bc1; n = 2048; outIdx = IC_N1; }
  else if (blockIdx.x == 1) { a = bc2; n = 256;  outIdx = IC_N2; }
  else                      { a = bc4; n = 32;   outIdx = IC_N4; }
  int t = threadIdx.x;
  int i0 = t, i1 = t + 1024;
  int v0 = (i0 < n) ? a[i0] : 0;
  int v1 = (i1 < n) ? a[i1] : 0;
  sA[i0] = v0; sA[i1] = v1;
  __syncthreads();
  int* src = sA; int* dst = sB;
  for (int st = 1; st < 2048; st <<= 1) {
    int x0 = src[i0]; if (i0 >= st) x0 += src[i0 - st];
    int x1 = src[i1]; if (i1 >= st) x1 += src[i1 - st];
    dst[i0] = x0; dst[i1] = x1;
    __syncthreads();
    int* tmp = src; src = dst; dst = tmp;
  }
  if (i0 < n) a[i0] = src[i0] - v0;
  if (i1 < n) a[i1] = src[i1] - v1;
  if (t == 0) cnts[outIdx] = src[2047];
}

// ---------- scatter ----------
__global__ __launch_bounds__(256) void k_scatter(const int* __restrict__ m1,
                                                 const int* __restrict__ m2,
                                                 const int* __restrict__ m4,
                                                 const int* __restrict__ bc1,
                                                 const int* __restrict__ bc2,
                                                 const int* __restrict__ bc4,
                                                 int* __restrict__ list1,
                                                 int* __restrict__ list2,
                                                 int* __restrict__ list4) {
  __shared__ int s_w[4];
  int bid = blockIdx.x, t = threadIdx.x;
  const int* mask; const int* base; int* list; int lb;
  if (bid < 2048)      { mask = m1; base = bc1; list = list1; lb = bid; }
  else if (bid < 2304) { mask = m2; base = bc2; list = list2; lb = bid - 2048; }
  else                 { mask = m4; base = bc4; list = list4; lb = bid - 2304; }
  int idx = lb * 256 + t;
  int act = mask[idx];
  unsigned long long b = __ballot(act != 0);
  int lane = t & 63, wid = t >> 6;
  if (lane == 0) s_w[wid] = __popcll(b);
  __syncthreads();
  int wbase = 0;
  for (int i = 0; i < wid; i++) wbase += s_w[i];
  if (act) {
    int pre = __popcll(b & ((1ull << lane) - 1ull));
    list[base[lb] + wbase + pre] = idx;
  }
}

// ---------- neighbor bitmask precompute: mode = blockIdx.y ----------
__global__ __launch_bounds__(256) void k_nbr(const int* __restrict__ m1,
                                             const int* __restrict__ m2,
                                             const int* __restrict__ m4,
                                             const int* __restrict__ list1,
                                             const int* __restrict__ list2,
                                             const int* __restrict__ list4,
                                             const int* __restrict__ cnts,
                                             int* __restrict__ nb1,
                                             int* __restrict__ nb2,
                                             int* __restrict__ nb4,
                                             int* __restrict__ nbt3,
                                             int* __restrict__ nbt2) {
  int mode = blockIdx.y;
  int tid = blockIdx.x * 256 + threadIdx.x;
  int stride = gridDim.x * 256;
  if (mode == 0) {                 // conv1: list1, stride1 taps over m1 (64 grid)
    int n = cnts[IC_N1];
    for (int i = tid; i < n; i += stride) {
      int v = list1[i];
      int vx = v & 63, vy = (v >> 6) & 63, vz = (v >> 12) & 63, vb = v >> 18;
      unsigned wbits = 0; int tap = 0;
#pragma unroll
      for (int kd = 0; kd < 3; kd++) { int d = vz + kd - 1; int okd = ((unsigned)d < 64u); int dc = okd ? d : 0;
#pragma unroll
        for (int kh = 0; kh < 3; kh++) { int h = vy + kh - 1; int okh = ((unsigned)h < 64u); int hc = okh ? h : 0;
#pragma unroll
          for (int kw = 0; kw < 3; kw++) { int ww = vx + kw - 1; int okw = ((unsigned)ww < 64u); int wc = okw ? ww : 0;
            int ni = ((vb * 64 + dc) * 64 + hc) * 64 + wc;
            int bit = (okd & okh & okw) & (m1[ni] != 0);
            wbits |= ((unsigned)bit) << tap; tap++;
          } } }
      nb1[i] = (int)wbits;
    }
  } else if (mode == 1) {          // conv2: list2, stride2 taps over m1 (64 grid)
    int n = cnts[IC_N2];
    for (int i = tid; i < n; i += stride) {
      int v = list2[i];
      int vx = v & 31, vy = (v >> 5) & 31, vz = (v >> 10) & 31, vb = v >> 15;
      unsigned wbits = 0; int tap = 0;
#pragma unroll
      for (int kd = 0; kd < 3; kd++) { int d = 2 * vz + kd - 1; int okd = (d >= 0); int dc = okd ? d : 0;
#pragma unroll
        for (int kh = 0; kh < 3; kh++) { int h = 2 * vy + kh - 1; int okh = (h >= 0); int hc = okh ? h : 0;
#pragma unroll
          for (int kw = 0; kw < 3; kw++) { int ww = 2 * vx + kw - 1; int okw = (ww >= 0); int wc = okw ? ww : 0;
            int ni = ((vb * 64 + dc) * 64 + hc) * 64 + wc;
            int bit = (okd & okh & okw) & (m1[ni] != 0);
            wbits |= ((unsigned)bit) << tap; tap++;
          } } }
      nb2[i] = (int)wbits;
    }
  } else if (mode == 2) {          // conv3: list4, stride2 taps over m2 (32 grid)
    int n = cnts[IC_N4];
    for (int i = tid; i < n; i += stride) {
      int v = list4[i];
      int vx = v & 15, vy = (v >> 4) & 15, vz = (v >> 8) & 15, vb = v >> 12;
      unsigned wbits = 0; int tap = 0;
#pragma unroll
      for (int kd = 0; kd < 3; kd++) { int d = 2 * vz + kd - 1; int okd = (d >= 0); int dc = okd ? d : 0;
#pragma unroll
        for (int kh = 0; kh < 3; kh++) { int h = 2 * vy + kh - 1; int okh = (h >= 0); int hc = okh ? h : 0;
#pragma unroll
          for (int kw = 0; kw < 3; kw++) { int ww = 2 * vx + kw - 1; int okw = (ww >= 0); int wc = okw ? ww : 0;
            int ni = ((vb * 32 + dc) * 32 + hc) * 32 + wc;
            int bit = (okd & okh & okw) & (m2[ni] != 0);
            wbits |= ((unsigned)bit) << tap; tap++;
          } } }
      nb4[i] = (int)wbits;
    }
  } else if (mode == 3) {          // convt3: list2, transpose combos over m4 (16 grid)
    int n = cnts[IC_N2];
    for (int i = tid; i < n; i += stride) {
      int v = list2[i];
      int px = v & 31, py = (v >> 5) & 31, pz = (v >> 10) & 31, vb = v >> 15;
      int czv[2], kzv[2], okz[2], cyv[2], kyv[2], oky[2], cxv[2], kxv[2], okx[2];
      ttaps(pz, 16, czv, kzv, okz);
      ttaps(py, 16, cyv, kyv, oky);
      ttaps(px, 16, cxv, kxv, okx);
      unsigned wbits = 0; int comb = 0;
#pragma unroll
      for (int dz = 0; dz < 2; dz++)
#pragma unroll
        for (int dy = 0; dy < 2; dy++)
#pragma unroll
          for (int dx = 0; dx < 2; dx++) {
            int ni = ((vb * 16 + czv[dz]) * 16 + cyv[dy]) * 16 + cxv[dx];
            int bit = (okz[dz] & oky[dy] & okx[dx]) & (m4[ni] != 0);
            wbits |= ((unsigned)bit) << comb; comb++;
          }
      nbt3[i] = (int)wbits;
    }
  } else {                         // convt2: list1, transpose combos over m2 (32 grid)
    int n = cnts[IC_N1];
    for (int i = tid; i < n; i += stride) {
      int v = list1[i];
      int px = v & 63, py = (v >> 6) & 63, pz = (v >> 12) & 63, vb = v >> 18;
      int czv[2], kzv[2], okz[2], cyv[2], kyv[2], oky[2], cxv[2], kxv[2], okx[2];
      ttaps(pz, 32, czv, kzv, okz);
      ttaps(py, 32, cyv, kyv, oky);
      ttaps(px, 32, cxv, kxv, okx);
      unsigned wbits = 0; int comb = 0;
#pragma unroll
      for (int dz = 0; dz < 2; dz++)
#pragma unroll
        for (int dy = 0; dy < 2; dy++)
#pragma unroll
          for (int dx = 0; dx < 2; dx++) {
            int ni = ((vb * 32 + czv[dz]) * 32 + cyv[dy]) * 32 + cxv[dx];
            int bit = (okz[dz] & oky[dy] & okx[dx]) & (m2[ni] != 0);
            wbits |= ((unsigned)bit) << comb; comb++;
          }
      nbt2[i] = (int)wbits;
    }
  }
}

// ---------- conv1: thread = voxel, 8 acc; bit-gated taps ----------
__global__ __launch_bounds__(256) void k_conv1(const float* __restrict__ x,
                                               const int* __restrict__ nb1,
                                               const int* __restrict__ list1,
                                               const int* __restrict__ cnts,
                                               const float* __restrict__ w,
                                               float* __restrict__ h1,
                                               float* __restrict__ stats) {
  __shared__ float s_w[27 * 32];
  __shared__ float s_sum[8], s_sq[8];
  int t = threadIdx.x;
  { const float4* w4 = (const float4*)w; float4* sw4 = (float4*)s_w;
    for (int i = t; i < 216; i += 256) sw4[i] = w4[i]; }
  if (t < 8) { s_sum[t] = 0.f; s_sq[t] = 0.f; }
  __syncthreads();
  int n = cnts[IC_N1];
  float sum[8], sq[8];
#pragma unroll
  for (int c = 0; c < 8; c++) { sum[c] = 0.f; sq[c] = 0.f; }
  for (int i = blockIdx.x * 256 + t; i < n; i += gridDim.x * 256) {
    int v = list1[i];
    unsigned nbr = (unsigned)nb1[i];
    int vx = v & 63, vy = (v >> 6) & 63, vz = (v >> 12) & 63, vb = v >> 18;
    float acc[8];
#pragma unroll
    for (int c = 0; c < 8; c++) acc[c] = 0.f;
    int tap = 0;
#pragma unroll
    for (int kd = 0; kd < 3; kd++)
#pragma unroll
      for (int kh = 0; kh < 3; kh++)
#pragma unroll
        for (int kw = 0; kw < 3; kw++) {
          if (nbr & (1u << tap)) {
            int ni = ((vb * 64 + vz + kd - 1) * 64 + vy + kh - 1) * 64 + vx + kw - 1;
            float4 ip = *(const float4*)(x + (size_t)ni * 4);
            const float* wp = s_w + tap * 32;
#pragma unroll
            for (int co = 0; co < 8; co++) {
              float a = fmaf(ip.x, wp[co], acc[co]);
              a = fmaf(ip.y, wp[8 + co], a);
              a = fmaf(ip.z, wp[16 + co], a);
              acc[co] = fmaf(ip.w, wp[24 + co], a);
            }
          }
          tap++;
        }
    float4* hp = (float4*)(h1 + (size_t)v * 8);
    hp[0] = make_float4(acc[0], acc[1], acc[2], acc[3]);
    hp[1] = make_float4(acc[4], acc[5], acc[6], acc[7]);
#pragma unroll
    for (int c = 0; c < 8; c++) { sum[c] += acc[c]; sq[c] += acc[c] * acc[c]; }
  }
  stat_flush8(sum, sq, s_sum, s_sq, t);
  __syncthreads();
  if (t < 8) {
    if (s_sum[t] != 0.f) atomicAdd(&stats[ST_SUM1 + t], s_sum[t]);
    if (s_sq[t]  != 0.f) atomicAdd(&stats[ST_SQ1 + t], s_sq[t]);
  }
}

// ---------- conv2: group g of 8 co; BN1+relu inline; bit-gated ----------
__global__ __launch_bounds__(256) void k_conv2(const float* __restrict__ h1,
                                               const int* __restrict__ nb2,
                                               const int* __restrict__ list2,
                                               const int* __restrict__ cnts,
                                               const float* __restrict__ w,
                                               const float* __restrict__ g1,
                                               const float* __restrict__ b1,
                                               float* __restrict__ s2,
                                               float* __restrict__ stats) {
  __shared__ float s_w[27 * 8 * 8];
  __shared__ float s_sc[8], s_bi[8];
  __shared__ float s_sum[8], s_sq[8];
  int t = threadIdx.x, g = blockIdx.y;
  for (int i = t; i < 432; i += 256) {
    int r = i >> 1, half = i & 1;
    *(float4*)(s_w + r * 8 + half * 4) = *(const float4*)(w + r * 16 + g * 8 + half * 4);
  }
  if (t < 8) {
    float cnt = fmaxf((float)cnts[IC_N1], 1.f);
    float mean = stats[ST_SUM1 + t] / cnt;
    float var = fmaxf(stats[ST_SQ1 + t] / cnt - mean * mean, 0.f);
    float sc = g1[t] * rsqrtf(var + EPSBN);
    s_sc[t] = sc; s_bi[t] = b1[t] - mean * sc;
    s_sum[t] = 0.f; s_sq[t] = 0.f;
  }
  __syncthreads();
  int n = cnts[IC_N2];
  float sum[8], sq[8];
#pragma unroll
  for (int c = 0; c < 8; c++) { sum[c] = 0.f; sq[c] = 0.f; }
  for (int i = blockIdx.x * 256 + t; i < n; i += gridDim.x * 256) {
    int v = list2[i];
    unsigned nbr = (unsigned)nb2[i];
    int vx = v & 31, vy = (v >> 5) & 31, vz = (v >> 10) & 31, vb = v >> 15;
    float acc[8];
#pragma unroll
    for (int c = 0; c < 8; c++) acc[c] = 0.f;
    int tap = 0;
#pragma unroll
    for (int kd = 0; kd < 3; kd++)
#pragma unroll
      for (int kh = 0; kh < 3; kh++)
#pragma unroll
        for (int kw = 0; kw < 3; kw++) {
          if (nbr & (1u << tap)) {
            int ni = ((vb * 64 + 2 * vz + kd - 1) * 64 + 2 * vy + kh - 1) * 64 + 2 * vx + kw - 1;
            float4 i0 = *(const float4*)(h1 + (size_t)ni * 8);
            float4 i1 = *(const float4*)(h1 + (size_t)ni * 8 + 4);
            float r[8] = {i0.x, i0.y, i0.z, i0.w, i1.x, i1.y, i1.z, i1.w};
            const float* wp = s_w + tap * 64;
#pragma unroll
            for (int ci = 0; ci < 8; ci++) {
              float vv = fmaxf(fmaf(r[ci], s_sc[ci], s_bi[ci]), 0.f);
#pragma unroll
              for (int co = 0; co < 8; co++) acc[co] = fmaf(vv, wp[ci * 8 + co], acc[co]);
            }
          }
          tap++;
        }
    float4* sp = (float4*)(s2 + (size_t)v * 16 + g * 8);
    sp[0] = make_float4(acc[0], acc[1], acc[2], acc[3]);
    sp[1] = make_float4(acc[4], acc[5], acc[6], acc[7]);
#pragma unroll
    for (int c = 0; c < 8; c++) { sum[c] += acc[c]; sq[c] += acc[c] * acc[c]; }
  }
  stat_flush8(sum, sq, s_sum, s_sq, t);
  __syncthreads();
  if (t < 8) {
    if (s_sum[t] != 0.f) atomicAdd(&stats[ST_SUM2 + g * 8 + t], s_sum[t]);
    if (s_sq[t]  != 0.f) atomicAdd(&stats[ST_SQ2 + g * 8 + t], s_sq[t]);
  }
}

// ---------- conv3: group g of 8 co (4 groups); BN2+relu inline; bit-gated ----------
__global__ __launch_bounds__(256) void k_conv3(const float* __restrict__ s2raw,
                                               const int* __restrict__ nb4,
                                               const int* __restrict__ list4,
                                               const int* __restrict__ cnts,
                                               const float* __restrict__ w,
                                               const float* __restrict__ g2,
                                               const float* __restrict__ b2,
                                               float* __restrict__ h3,
                                               float* __restrict__ stats) {
  __shared__ float s_w[27 * 16 * 8];
  __shared__ float s_sc[16], s_bi[16];
  __shared__ float s_sum[8], s_sq[8];
  int t = threadIdx.x, g = blockIdx.y;
  for (int i = t; i < 864; i += 256) {
    int r = i >> 1, half = i & 1;
    *(float4*)(s_w + r * 8 + half * 4) = *(const float4*)(w + r * 32 + g * 8 + half * 4);
  }
  if (t < 16) {
    float cnt = fmaxf((float)cnts[IC_N2], 1.f);
    float mean = stats[ST_SUM2 + t] / cnt;
    float var = fmaxf(stats[ST_SQ2 + t] / cnt - mean * mean, 0.f);
    float sc = g2[t] * rsqrtf(var + EPSBN);
    s_sc[t] = sc; s_bi[t] = b2[t] - mean * sc;
  }
  if (t < 8) { s_sum[t] = 0.f; s_sq[t] = 0.f; }
  __syncthreads();
  int n = cnts[IC_N4];
  float sum[8], sq[8];
#pragma unroll
  for (int c = 0; c < 8; c++) { sum[c] = 0.f; sq[c] = 0.f; }
  for (int i = blockIdx.x * 256 + t; i < n; i += gridDim.x * 256) {
    int v = list4[i];
    unsigned nbr = (unsigned)nb4[i];
    int vx = v & 15, vy = (v >> 4) & 15, vz = (v >> 8) & 15, vb = v >> 12;
    float acc[8];
#pragma unroll
    for (int c = 0; c < 8; c++) acc[c] = 0.f;
    int tap = 0;
#pragma unroll
    for (int kd = 0; kd < 3; kd++)
#pragma unroll
      for (int kh = 0; kh < 3; kh++)
#pragma unroll
        for (int kw = 0; kw < 3; kw++) {
          if (nbr & (1u << tap)) {
            int ni = ((vb * 32 + 2 * vz + kd - 1) * 32 + 2 * vy + kh - 1) * 32 + 2 * vx + kw - 1;
            const float4* ip = (const float4*)(s2raw + (size_t)ni * 16);
            const float* wp = s_w + tap * 128;
#pragma unroll
            for (int cq = 0; cq < 4; cq++) {
              float4 q = ip[cq];
              float rr[4] = {q.x, q.y, q.z, q.w};
#pragma unroll
              for (int j = 0; j < 4; j++) {
                int ci = cq * 4 + j;
                float vv = fmaxf(fmaf(rr[j], s_sc[ci], s_bi[ci]), 0.f);
#pragma unroll
                for (int co = 0; co < 8; co++) acc[co] = fmaf(vv, wp[ci * 8 + co], acc[co]);
              }
            }
          }
          tap++;
        }
    float4* hp = (float4*)(h3 + (size_t)v * 32 + g * 8);
    hp[0] = make_float4(acc[0], acc[1], acc[2], acc[3]);
    hp[1] = make_float4(acc[4], acc[5], acc[6], acc[7]);
#pragma unroll
    for (int c = 0; c < 8; c++) { sum[c] += acc[c]; sq[c] += acc[c] * acc[c]; }
  }
  stat_flush8(sum, sq, s_sum, s_sq, t);
  __syncthreads();
  if (t < 8) {
    if (s_sum[t] != 0.f) atomicAdd(&stats[ST_SUM3 + g * 8 + t], s_sum[t]);
    if (s_sq[t]  != 0.f) atomicAdd(&stats[ST_SQ3 + g * 8 + t], s_sq[t]);
  }
}

// ---------- convt3: group g of 8 co; BN3+relu inline; bit-gated ----------
__global__ __launch_bounds__(256) void k_convt3(const float* __restrict__ h3raw,
                                                const int* __restrict__ nbt3,
                                                const int* __restrict__ list2,
                                                const int* __restrict__ cnts,
                                                const float* __restrict__ w,
                                                const float* __restrict__ g3,
                                                const float* __restrict__ b3,
                                                float* __restrict__ t3,
                                                float* __restrict__ stats) {
  __shared__ float s_w[27 * 32 * 8];
  __shared__ float s_sc[32], s_bi[32];
  __shared__ float s_sum[8], s_sq[8];
  int t = threadIdx.x, g = blockIdx.y;
  for (int i = t; i < 1728; i += 256) {
    int r = i >> 1, half = i & 1;
    *(float4*)(s_w + r * 8 + half * 4) = *(const float4*)(w + r * 16 + g * 8 + half * 4);
  }
  if (t < 32) {
    float cnt = fmaxf((float)cnts[IC_N4], 1.f);
    float mean = stats[ST_SUM3 + t] / cnt;
    float var = fmaxf(stats[ST_SQ3 + t] / cnt - mean * mean, 0.f);
    float sc = g3[t] * rsqrtf(var + EPSBN);
    s_sc[t] = sc; s_bi[t] = b3[t] - mean * sc;
  }
  if (t < 8) { s_sum[t] = 0.f; s_sq[t] = 0.f; }
  __syncthreads();
  int n = cnts[IC_N2];
  float sum[8], sq[8];
#pragma unroll
  for (int c = 0; c < 8; c++) { sum[c] = 0.f; sq[c] = 0.f; }
  for (int i = blockIdx.x * 256 + t; i < n; i += gridDim.x * 256) {
    int v = list2[i];
    unsigned nbr = (unsigned)nbt3[i];
    int px = v & 31, py = (v >> 5) & 31, pz = (v >> 10) & 31, vb = v >> 15;
    int czv[2], kzv[2], okz[2], cyv[2], kyv[2], oky[2], cxv[2], kxv[2], okx[2];
    ttaps(pz, 16, czv, kzv, okz);
    ttaps(py, 16, cyv, kyv, oky);
    ttaps(px, 16, cxv, kxv, okx);
    float acc[8];
#pragma unroll
    for (int c = 0; c < 8; c++) acc[c] = 0.f;
    int comb = 0;
#pragma unroll
    for (int dz = 0; dz < 2; dz++)
#pragma unroll
      for (int dy = 0; dy < 2; dy++)
#pragma unroll
        for (int dx = 0; dx < 2; dx++) {
          if (nbr & (1u << comb)) {
            int ni = ((vb * 16 + czv[dz]) * 16 + cyv[dy]) * 16 + cxv[dx];
            const float4* ip = (const float4*)(h3raw + (size_t)ni * 32);
            const float* wp = s_w + ((kzv[dz] * 3 + kyv[dy]) * 3 + kxv[dx]) * 256;
#pragma unroll
            for (int cq = 0; cq < 8; cq++) {
              float4 q = ip[cq];
              float rr[4] = {q.x, q.y, q.z, q.w};
#pragma unroll
              for (int j = 0; j < 4; j++) {
                int ci = cq * 4 + j;
                float vv = fmaxf(fmaf(rr[j], s_sc[ci], s_bi[ci]), 0.f);
#pragma unroll
                for (int co = 0; co < 8; co++) acc[co] = fmaf(vv, wp[ci * 8 + co], acc[co]);
              }
            }
          }
          comb++;
        }
    float4* op = (float4*)(t3 + (size_t)v * 16 + g * 8);
    op[0] = make_float4(acc[0], acc[1], acc[2], acc[3]);
    op[1] = make_float4(acc[4], acc[5], acc[6], acc[7]);
#pragma unroll
    for (int c = 0; c < 8; c++) { sum[c] += acc[c]; sq[c] += acc[c] * acc[c]; }
  }
  stat_flush8(sum, sq, s_sum, s_sq, t);
  __syncthreads();
  if (t < 8) {
    if (s_sum[t] != 0.f) atomicAdd(&stats[ST_SUM3T + g * 8 + t], s_sum[t]);
    if (s_sq[t]  != 0.f) atomicAdd(&stats[ST_SQ3T + g * 8 + t], s_sq[t]);
  }
}

// ---------- convt2: group g of 8 co; concat; bit-gated; raw -> d_out ----------
__global__ __launch_bounds__(256) void k_convt2(const float* __restrict__ t3raw,
                                                const float* __restrict__ s2raw,
                                                const int* __restrict__ nbt2,
                                                const int* __restrict__ list1,
                                                const int* __restrict__ cnts,
                                                const float* __restrict__ w,
                                                const float* __restrict__ g3t,
                                                const float* __restrict__ b3t,
                                                const float* __restrict__ g2,
                                                const float* __restrict__ b2,
                                                float* __restrict__ outraw,
                                                float* __restrict__ stats) {
  __shared__ float s_w[27 * 32 * 8];
  __shared__ float s_sct[16], s_bit[16], s_sc2[16], s_bi2[16];
  __shared__ float s_sum[8], s_sq[8];
  int t = threadIdx.x, g = blockIdx.y;
  for (int i = t; i < 1728; i += 256) {
    int r = i >> 1, half = i & 1;
    *(float4*)(s_w + r * 8 + half * 4) = *(const float4*)(w + r * 16 + g * 8 + half * 4);
  }
  if (t < 16) {
    float cnt = fmaxf((float)cnts[IC_N2], 1.f);
    float mean = stats[ST_SUM3T + t] / cnt;
    float var = fmaxf(stats[ST_SQ3T + t] / cnt - mean * mean, 0.f);
    float sc = g3t[t] * rsqrtf(var + EPSBN);
    s_sct[t] = sc; s_bit[t] = b3t[t] - mean * sc;
    float mean2 = stats[ST_SUM2 + t] / cnt;
    float var2 = fmaxf(stats[ST_SQ2 + t] / cnt - mean2 * mean2, 0.f);
    float sc2 = g2[t] * rsqrtf(var2 + EPSBN);
    s_sc2[t] = sc2; s_bi2[t] = b2[t] - mean2 * sc2;
  }
  if (t < 8) { s_sum[t] = 0.f; s_sq[t] = 0.f; }
  __syncthreads();
  int n = cnts[IC_N1];
  float sum[8], sq[8];
#pragma unroll
  for (int c = 0; c < 8; c++) { sum[c] = 0.f; sq[c] = 0.f; }
  for (int i = blockIdx.x * 256 + t; i < n; i += gridDim.x * 256) {
    int v = list1[i];
    unsigned nbr = (unsigned)nbt2[i];
    int px = v & 63, py = (v >> 6) & 63, pz = (v >> 12) & 63, vb = v >> 18;
    int czv[2], kzv[2], okz[2], cyv[2], kyv[2], oky[2], cxv[2], kxv[2], okx[2];
    ttaps(pz, 32, czv, kzv, okz);
    ttaps(py, 32, cyv, kyv, oky);
    ttaps(px, 32, cxv, kxv, okx);
    float acc[8];
#pragma unroll
    for (int c = 0; c < 8; c++) acc[c] = 0.f;
    int comb = 0;
#pragma unroll
    for (int dz = 0; dz < 2; dz++)
#pragma unroll
      for (int dy = 0; dy < 2; dy++)
#pragma unroll
        for (int dx = 0; dx < 2; dx++) {
          if (nbr & (1u << comb)) {
            int ni = ((vb * 32 + czv[dz]) * 32 + cyv[dy]) * 32 + cxv[dx];
            const float4* tp = (const float4*)(t3raw + (size_t)ni * 16);
            const float4* sp = (const float4*)(s2raw + (size_t)ni * 16);
            const float* wp = s_w + ((kzv[dz] * 3 + kyv[dy]) * 3 + kxv[dx]) * 256;
#pragma unroll
            for (int cq = 0; cq < 4; cq++) {
              float4 q = tp[cq];
              float rr[4] = {q.x, q.y, q.z, q.w};
#pragma unroll
              for (int j = 0; j < 4; j++) {
                int ci = cq * 4 + j;
                float vv = fmaxf(fmaf(rr[j], s_sct[ci], s_bit[ci]), 0.f);
#pragma unroll
                for (int co = 0; co < 8; co++) acc[co] = fmaf(vv, wp[ci * 8 + co], acc[co]);
              }
            }
#pragma unroll
            for (int cq = 0; cq < 4; cq++) {
              float4 q = sp[cq];
              float rr[4] = {q.x, q.y, q.z, q.w};
#pragma unroll
              for (int j = 0; j < 4; j++) {
                int ci = cq * 4 + j;
                float vv = fmaf(rr[j], s_sc2[ci], s_bi2[ci]);
#pragma unroll
                for (int co = 0; co < 8; co++) acc[co] = fmaf(vv, wp[(16 + ci) * 8 + co], acc[co]);
              }
            }
          }
          comb++;
        }
    float4* op = (float4*)(outraw + (size_t)v * 16 + g * 8);
    op[0] = make_float4(acc[0], acc[1], acc[2], acc[3]);
    op[1] = make_float4(acc[4], acc[5], acc[6], acc[7]);
#pragma unroll
    for (int c = 0; c < 8; c++) { sum[c] += acc[c]; sq[c] += acc[c] * acc[c]; }
  }
  stat_flush8(sum, sq, s_sum, s_sq, t);
  __syncthreads();
  if (t < 8) {
    if (s_sum[t] != 0.f) atomicAdd(&stats[ST_SUM2T + g * 8 + t], s_sum[t]);
    if (s_sq[t]  != 0.f) atomicAdd(&stats[ST_SQ2T + g * 8 + t], s_sq[t]);
  }
}

// ---------- final (DENSE): BN2t+relu(out) concat BN1(h1) -> 1x1; zeros for inactive ----------
__global__ __launch_bounds__(256) void k_final(float* __restrict__ out,
                                               const float* __restrict__ h1raw,
                                               const int* __restrict__ m1,
                                               const int* __restrict__ cnts,
                                               const float* __restrict__ g2t,
                                               const float* __restrict__ b2t,
                                               const float* __restrict__ g1,
                                               const float* __restrict__ b1,
                                               const float* __restrict__ w1x1,
                                               const float* __restrict__ stats) {
  __shared__ float s_sc[16], s_bi[16], s_sc1[8], s_bi1[8], s_w[384];
  int t = threadIdx.x;
  for (int i = t; i < 384; i += 256) s_w[i] = w1x1[i];
  if (t < 16) {
    float cnt = fmaxf((float)cnts[IC_N1], 1.f);
    float mean = stats[ST_SUM2T + t] / cnt;
    float var = fmaxf(stats[ST_SQ2T + t] / cnt - mean * mean, 0.f);
    float sc = g2t[t] * rsqrtf(var + EPSBN);
    s_sc[t] = sc; s_bi[t] = b2t[t] - mean * sc;
  }
  if (t < 8) {
    float cnt = fmaxf((float)cnts[IC_N1], 1.f);
    float mean = stats[ST_SUM1 + t] / cnt;
    float var = fmaxf(stats[ST_SQ1 + t] / cnt - mean * mean, 0.f);
    float sc = g1[t] * rsqrtf(var + EPSBN);
    s_sc1[t] = sc; s_bi1[t] = b1[t] - mean * sc;
  }
  __syncthreads();
  int v = blockIdx.x * 256 + t;
  float* op = out + (size_t)v * 16;
  float4* op4 = (float4*)op;
  if (!m1[v]) {
    float4 z = {0.f, 0.f, 0.f, 0.f};
    op4[0] = z; op4[1] = z; op4[2] = z; op4[3] = z;
    return;
  }
  float t2[16];
  {
#pragma unroll
    for (int cq = 0; cq < 4; cq++) {
      float4 q = op4[cq];
      t2[cq * 4 + 0] = fmaxf(fmaf(q.x, s_sc[cq * 4 + 0], s_bi[cq * 4 + 0]), 0.f);
      t2[cq * 4 + 1] = fmaxf(fmaf(q.y, s_sc[cq * 4 + 1], s_bi[cq * 4 + 1]), 0.f);
      t2[cq * 4 + 2] = fmaxf(fmaf(q.z, s_sc[cq * 4 + 2], s_bi[cq * 4 + 2]), 0.f);
      t2[cq * 4 + 3] = fmaxf(fmaf(q.w, s_sc[cq * 4 + 3], s_bi[cq * 4 + 3]), 0.f);
    }
  }
  float s1v[8];
  {
    const float4* sp4 = (const float4*)(h1raw + (size_t)v * 8);
#pragma unroll
    for (int cq = 0; cq < 2; cq++) {
      float4 q = sp4[cq];
      s1v[cq * 4 + 0] = fmaf(q.x, s_sc1[cq * 4 + 0], s_bi1[cq * 4 + 0]);
      s1v[cq * 4 + 1] = fmaf(q.y, s_sc1[cq * 4 + 1], s_bi1[cq * 4 + 1]);
      s1v[cq * 4 + 2] = fmaf(q.z, s_sc1[cq * 4 + 2], s_bi1[cq * 4 + 2]);
      s1v[cq * 4 + 3] = fmaf(q.w, s_sc1[cq * 4 + 3], s_bi1[cq * 4 + 3]);
    }
  }
  float o[16];
#pragma unroll
  for (int oc = 0; oc < 16; oc++) o[oc] = 0.f;
#pragma unroll
  for (int c = 0; c < 16; c++) {
    float vv = t2[c];
#pragma unroll
    for (int oc = 0; oc < 16; oc++) o[oc] = fmaf(vv, s_w[c * 16 + oc], o[oc]);
  }
#pragma unroll
  for (int c = 0; c < 8; c++) {
    float vv = s1v[c];
#pragma unroll
    for (int oc = 0; oc < 16; oc++) o[oc] = fmaf(vv, s_w[(16 + c) * 16 + oc], o[oc]);
  }
#pragma unroll
  for (int cq = 0; cq < 4; cq++) {
    float4 q = {o[cq * 4 + 0], o[cq * 4 + 1], o[cq * 4 + 2], o[cq * 4 + 3]};
    op4[cq] = q;
  }
}

extern "C" void kernel_launch(void* const* d_in, const int* in_sizes, int n_in,
                              void* d_out, int out_size, void* d_ws, size_t ws_size,
                              hipStream_t stream) {
  const float* x    = (const float*)d_in[0];
  const void*  mraw = d_in[1];
  const float* w1   = (const float*)d_in[2];
  const float* g1   = (const float*)d_in[3];
  const float* b1   = (const float*)d_in[4];
  const float* w2   = (const float*)d_in[5];
  const float* g2   = (const float*)d_in[6];
  const float* b2   = (const float*)d_in[7];
  const float* w3   = (const float*)d_in[8];
  const float* g3   = (const float*)d_in[9];
  const float* b3   = (const float*)d_in[10];
  const float* w3t  = (const float*)d_in[11];
  const float* g3t  = (const float*)d_in[12];
  const float* b3t  = (const float*)d_in[13];
  const float* w2t  = (const float*)d_in[14];
  const float* g2t  = (const float*)d_in[15];
  const float* b2t  = (const float*)d_in[16];
  const float* w1x1 = (const float*)d_in[17];

  float* ws = (float*)d_ws;
  float* stats = ws;
  int* cnts = (int*)ws;
  int* flags = (int*)(ws + FLAG_OFF);
  int* m1c = (int*)(ws + OFF_M1C);
  int* m2  = (int*)(ws + OFF_M2);
  int* m4  = (int*)(ws + OFF_M4);
  float* h1 = ws + OFF_H1;
  float* s2 = ws + OFF_S2;
  float* h3 = ws + OFF_H3;
  float* t3 = ws + OFF_T3;
  int* list1 = (int*)(ws + OFF_L1);
  int* list2 = (int*)(ws + OFF_L2);
  int* list4 = (int*)(ws + OFF_L4);
  int* bc1 = (int*)(ws + OFF_BC1);
  int* bc2 = (int*)(ws + OFF_BC2);
  int* bc4 = (int*)(ws + OFF_BC4);
  int* nb1  = (int*)(ws + OFF_NB1);
  int* nb2  = (int*)(ws + OFF_NB2);
  int* nb4  = (int*)(ws + OFF_NB4);
  int* nbt3 = (int*)(ws + OFF_NBT3);
  int* nbt2 = (int*)(ws + OFF_NBT2);
  float* out = (float*)d_out;

  hipMemsetAsync(ws, 0, ST_ZERO * sizeof(float), stream);
  k_detect<<<256, 256, 0, stream>>>((const unsigned int*)mraw, flags);
  k_canon<<<NVOX1 / 256, 256, 0, stream>>>(mraw, m1c, flags, bc1);
  k_down1<<<NVOX2 / 256, 256, 0, stream>>>(m1c, m2, bc2);
  k_down2<<<NVOX4 / 256, 256, 0, stream>>>(m2, m4, bc4);
  k_scan<<<3, 1024, 0, stream>>>(bc1, bc2, bc4, cnts);
  k_scatter<<<2048 + 256 + 32, 256, 0, stream>>>(m1c, m2, m4, bc1, bc2, bc4, list1, list2, list4);
  k_nbr<<<dim3(256, 5), 256, 0, stream>>>(m1c, m2, m4, list1, list2, list4, cnts,
                                          nb1, nb2, nb4, nbt3, nbt2);
  k_conv1<<<256, 256, 0, stream>>>(x, nb1, list1, cnts, w1, h1, stats);
  k_conv2<<<dim3(256, 2), 256, 0, stream>>>(h1, nb2, list2, cnts, w2, g1, b1, s2, stats);
  k_conv3<<<dim3(32, 4), 256, 0, stream>>>(s2, nb4, list4, cnts, w3, g2, b2, h3, stats);
  k_convt3<<<dim3(256, 2), 256, 0, stream>>>(h3, nbt3, list2, cnts, w3t, g3, b3, t3, stats);
  k_convt2<<<dim3(256, 2), 256, 0, stream>>>(t3, s2, nbt2, list1, cnts, w2t, g3t, b3t, g2, b2, out, stats);
  k_final<<<NVOX1 / 256, 256, 0, stream>>>(out, h1, m1c, cnts, g2t, b2t, g1, b1, w1x1, stats);
}